// Round 3
// baseline (185.617 us; speedup 1.0000x reference)
//
#include <hip/hip_runtime.h>
#include <hip/hip_bf16.h>

typedef short bf16x4 __attribute__((ext_vector_type(4)));
typedef short bf16x8 __attribute__((ext_vector_type(8)));
typedef float f32x4 __attribute__((ext_vector_type(4)));

__device__ inline unsigned short f2bf(float f) {
    union { float f; unsigned u; } c; c.f = f;
    unsigned r = c.u + 0x7fffu + ((c.u >> 16) & 1u);
    return (unsigned short)(r >> 16);
}
__device__ inline float bf2f(unsigned short u) {
    union { unsigned u; float f; } c; c.u = ((unsigned)u) << 16; return c.f;
}
__device__ inline unsigned cvt_pk_bf16(float lo, float hi) {
    unsigned r;
    asm("v_cvt_pk_bf16_f32 %0, %1, %2" : "=v"(r) : "v"(lo), "v"(hi));
    return r;
}
__device__ inline float fast_exp2(float x) {
#if __has_builtin(__builtin_amdgcn_exp2f)
    return __builtin_amdgcn_exp2f(x);
#else
    return __exp2f(x);
#endif
}

// ---------- fp32 -> bf16 convert ----------
__global__ __launch_bounds__(256) void k_f32_to_bf16(const float* __restrict__ in,
                                                     unsigned short* __restrict__ out, int n4) {
    int i = blockIdx.x * 256 + threadIdx.x;
    if (i >= n4) return;
    f32x4 v = *(const f32x4*)&in[(size_t)i * 4];
    ushort4 o;
    o.x = f2bf(v[0]); o.y = f2bf(v[1]); o.z = f2bf(v[2]); o.w = f2bf(v[3]);
    *(ushort4*)&out[(size_t)i * 4] = o;
}

// ---------- transpose [K][N] fp32 -> [N][K] bf16 ----------
__global__ __launch_bounds__(256) void k_transpose_bf16(const float* __restrict__ in,
                                                        unsigned short* __restrict__ out,
                                                        int K, int N) {
    int idx = blockIdx.x * 256 + threadIdx.x;
    if (idx >= N * K) return;
    int n = idx / K, k = idx % K;
    out[idx] = f2bf(in[(size_t)k * N + n]);
}

// ---------- transpose V slice of qkv -> v_t[b,h,d,j] bf16 ----------
__global__ __launch_bounds__(256) void transpose_v(const unsigned short* __restrict__ qkv,
                                                   unsigned short* __restrict__ vt) {
    const int bh = blockIdx.y, b = bh >> 3, h = bh & 7;
    const int j0 = blockIdx.x * 64;
    __shared__ unsigned short tile[64][72];
    const int t = threadIdx.x;
#pragma unroll
    for (int it = 0; it < 16; ++it) {
        int idx = it * 256 + t;
        int jr = idx >> 6, col = idx & 63;
        tile[jr][col] = qkv[(size_t)(b * 1024 + j0 + jr) * 1536 + 1024 + h * 64 + col];
    }
    __syncthreads();
#pragma unroll
    for (int it = 0; it < 16; ++it) {
        int idx = it * 256 + t;
        int dr = idx >> 6, jc = idx & 63;
        vt[((size_t)bh * 64 + dr) * 1024 + j0 + jc] = tile[jc][dr];
    }
}

// ---------- generic A[M,K] * B^T[N,K] bf16 MFMA GEMM ----------
template <int BM, int BN, int BK, bool OUT_BF16, bool HAS_BIAS>
__global__ __launch_bounds__(256) void gemm_bt(
    const unsigned short* __restrict__ A, int ldA, long long sA,
    const unsigned short* __restrict__ B, int ldB, long long sB,
    void* __restrict__ Cv, int ldC, long long sC,
    const float* __restrict__ bias, float scale, int K) {
    constexpr int PAD = 8, LDR = BK + PAD;
    __shared__ __align__(16) unsigned short As[BM * LDR];
    __shared__ __align__(16) unsigned short Bs[BN * LDR];

    const int tid = threadIdx.x;
    const int lane = tid & 63, wv = tid >> 6;
    const int wm = wv >> 1, wn = wv & 1;
    constexpr int WM = BM / 2, WN = BN / 2;
    constexpr int MF = WM / 16, NF = WN / 16;
    constexpr int KG = BK / 8;

    const int m0 = blockIdx.x * BM, n0 = blockIdx.y * BN;
    A += (long long)blockIdx.z * sA;
    B += (long long)blockIdx.z * sB;

    const int lr = lane & 15, lk = (lane >> 4) * 8;

    f32x4 acc[MF][NF];
#pragma unroll
    for (int m = 0; m < MF; ++m)
#pragma unroll
        for (int n = 0; n < NF; ++n) acc[m][n] = (f32x4){0.f, 0.f, 0.f, 0.f};

    for (int k0 = 0; k0 < K; k0 += BK) {
#pragma unroll
        for (int i = 0; i < BM * KG / 256; ++i) {
            int c = i * 256 + tid;
            int row = c / KG, kg = c % KG;
            *(bf16x8*)&As[row * LDR + kg * 8] =
                *(const bf16x8*)&A[(size_t)(m0 + row) * ldA + k0 + kg * 8];
        }
#pragma unroll
        for (int i = 0; i < BN * KG / 256; ++i) {
            int c = i * 256 + tid;
            int row = c / KG, kg = c % KG;
            *(bf16x8*)&Bs[row * LDR + kg * 8] =
                *(const bf16x8*)&B[(size_t)(n0 + row) * ldB + k0 + kg * 8];
        }
        __syncthreads();
#pragma unroll
        for (int kk = 0; kk < BK; kk += 32) {
            bf16x8 af[MF], bfr[NF];
#pragma unroll
            for (int m = 0; m < MF; ++m)
                af[m] = *(const bf16x8*)&As[(wm * WM + m * 16 + lr) * LDR + kk + lk];
#pragma unroll
            for (int n = 0; n < NF; ++n)
                bfr[n] = *(const bf16x8*)&Bs[(wn * WN + n * 16 + lr) * LDR + kk + lk];
#pragma unroll
            for (int m = 0; m < MF; ++m)
#pragma unroll
                for (int n = 0; n < NF; ++n)
                    acc[m][n] = __builtin_amdgcn_mfma_f32_16x16x32_bf16(af[m], bfr[n], acc[m][n], 0, 0, 0);
        }
        __syncthreads();
    }

    const int rb = (lane >> 4) * 4;
    const long long cbase = (long long)blockIdx.z * sC;
#pragma unroll
    for (int m = 0; m < MF; ++m) {
#pragma unroll
        for (int n = 0; n < NF; ++n) {
            int col = n0 + wn * WN + n * 16 + lr;
            float bv = HAS_BIAS ? bias[col] : 0.0f;
#pragma unroll
            for (int r = 0; r < 4; ++r) {
                int row = m0 + wm * WM + m * 16 + rb + r;
                float v = acc[m][n][r] * scale + bv;
                if constexpr (OUT_BF16)
                    ((unsigned short*)Cv)[cbase + (size_t)row * ldC + col] = f2bf(v);
                else
                    ((float*)Cv)[cbase + (size_t)row * ldC + col] = v;
            }
        }
    }
}

// ---------- fused attention v3 ----------
// grid 256 (b = blk&7, i-tile32 = blk>>3), 1024 thr = 16 waves = 8 heads x 2 j-parity groups.
// Pass1 (barrier-free): l = sum_j exp2(S) per (h,i). Pass2: p -> remix -> LN -> PV.
// Q prescaled by log2(e)/8 so MFMA output is the exp2 argument directly.
#define C_SCALE 0.18033688f

__global__ __launch_bounds__(1024, 4) void attn_fused(
    const unsigned short* __restrict__ qkv,   // [8192][1536] bf16
    const unsigned short* __restrict__ vt,    // [b*8+h][64][1024] bf16
    unsigned short* __restrict__ pvout,       // [8192][512] bf16
    const float* __restrict__ Wm,
    const float* __restrict__ ln_g, const float* __restrict__ ln_b) {
    const int blk = blockIdx.x;
    const int b = blk & 7, it = blk >> 3;
    const int i0 = it * 32;
    const int tid = threadIdx.x;
    const int lane = tid & 63;
    const int w = tid >> 6;
    const int h = w & 7, js = w >> 3;
    const int lr = lane & 15, qq = lane >> 4;

    // carved shared: Ps 36864 | Rs 36864 | lbuf 2048 ; osum reuses front 64KB after loops
    __shared__ __align__(16) char smem[75776];
    unsigned short* Ps = (unsigned short*)smem;             // [2][8][32][36]
    unsigned short* Rs = (unsigned short*)(smem + 36864);   // [2][8][32][36]
    float* lbuf = (float*)(smem + 73728);                   // [2][8][32]
    float* osum = (float*)smem;                             // [8][32][64] (after loops)

    // uniform weights -> scalar regs
    float wm[64];
#pragma unroll
    for (int z = 0; z < 64; ++z) wm[z] = Wm[z];
    float gam[8], bet[8];
#pragma unroll
    for (int z = 0; z < 8; ++z) { gam[z] = ln_g[z]; bet[z] = ln_b[z]; }

    // Q fragments (B-operand), prescaled by C_SCALE
    bf16x8 qf[2][2];
#pragma unroll
    for (int ni = 0; ni < 2; ++ni)
#pragma unroll
        for (int kk = 0; kk < 2; ++kk) {
            bf16x8 raw = *(const bf16x8*)&qkv[(size_t)(b * 1024 + i0 + ni * 16 + lr) * 1536 +
                                              h * 64 + kk * 32 + qq * 8];
            union { bf16x8 v; unsigned u[4]; } pk;
#pragma unroll
            for (int e = 0; e < 4; ++e)
                pk.u[e] = cvt_pk_bf16(bf2f((unsigned short)raw[2 * e]) * C_SCALE,
                                      bf2f((unsigned short)raw[2 * e + 1]) * C_SCALE);
            qf[ni][kk] = pk.v;
        }

    // K fragment pointers for this group's j-parity (t = js, js+2, ...)
    const unsigned short* kp0 = qkv + (size_t)(b * 1024 + js * 32 + lr) * 1536 + 512 + h * 64 + qq * 8;
    const unsigned short* kp1 = kp0 + (size_t)16 * 1536;

    // ---- pass 1: l = sum_j exp2(s*c), no barriers ----
    float lacc[2] = {0.f, 0.f};
    {
        const unsigned short* p0 = kp0;
        const unsigned short* p1 = kp1;
        for (int n = 0; n < 16; ++n) {
            bf16x8 k00 = *(const bf16x8*)(p0);
            bf16x8 k01 = *(const bf16x8*)(p0 + 32);
            bf16x8 k10 = *(const bf16x8*)(p1);
            bf16x8 k11 = *(const bf16x8*)(p1 + 32);
            p0 += 64 * 1536; p1 += 64 * 1536;
            f32x4 acc[2][2];
#pragma unroll
            for (int mf = 0; mf < 2; ++mf)
#pragma unroll
                for (int ni = 0; ni < 2; ++ni) acc[mf][ni] = (f32x4){0.f, 0.f, 0.f, 0.f};
#pragma unroll
            for (int ni = 0; ni < 2; ++ni) {
                acc[0][ni] = __builtin_amdgcn_mfma_f32_16x16x32_bf16(k00, qf[ni][0], acc[0][ni], 0, 0, 0);
                acc[0][ni] = __builtin_amdgcn_mfma_f32_16x16x32_bf16(k01, qf[ni][1], acc[0][ni], 0, 0, 0);
                acc[1][ni] = __builtin_amdgcn_mfma_f32_16x16x32_bf16(k10, qf[ni][0], acc[1][ni], 0, 0, 0);
                acc[1][ni] = __builtin_amdgcn_mfma_f32_16x16x32_bf16(k11, qf[ni][1], acc[1][ni], 0, 0, 0);
            }
#pragma unroll
            for (int ni = 0; ni < 2; ++ni)
#pragma unroll
                for (int mf = 0; mf < 2; ++mf)
#pragma unroll
                    for (int rr = 0; rr < 4; ++rr) lacc[ni] += fast_exp2(acc[mf][ni][rr]);
        }
    }
#pragma unroll
    for (int ni = 0; ni < 2; ++ni) {
        lacc[ni] += __shfl_xor(lacc[ni], 16);
        lacc[ni] += __shfl_xor(lacc[ni], 32);
    }
    if (qq == 0) {
        lbuf[(js * 8 + h) * 32 + lr] = lacc[0];
        lbuf[(js * 8 + h) * 32 + 16 + lr] = lacc[1];
    }
    __syncthreads();
    float llog[2];
    llog[0] = __log2f(lbuf[h * 32 + lr] + lbuf[(8 + h) * 32 + lr]);
    llog[1] = __log2f(lbuf[h * 32 + 16 + lr] + lbuf[(8 + h) * 32 + 16 + lr]);

    f32x4 o[2][4];
#pragma unroll
    for (int pp = 0; pp < 2; ++pp)
#pragma unroll
        for (int nd = 0; nd < 4; ++nd) o[pp][nd] = (f32x4){0.f, 0.f, 0.f, 0.f};

    // V pointers (B-operand of PV): vt[(b*8+h)*64 + nd*16+lr][t*32 + qq*8]
    const unsigned short* vp[4];
#pragma unroll
    for (int nd = 0; nd < 4; ++nd)
        vp[nd] = vt + ((size_t)(b * 8 + h) * 64 + nd * 16 + lr) * 1024 + js * 32 + qq * 8;

    const int psbase = (js * 8 + h) * 32 * 36;          // this wave's P slab
    const int jj = h * 4 + qq;                          // remix column owned by this lane

    // ---- pass 2 ----
    for (int n = 0; n < 16; ++n) {
        // S recompute
        bf16x8 k00 = *(const bf16x8*)(kp0);
        bf16x8 k01 = *(const bf16x8*)(kp0 + 32);
        bf16x8 k10 = *(const bf16x8*)(kp1);
        bf16x8 k11 = *(const bf16x8*)(kp1 + 32);
        kp0 += 64 * 1536; kp1 += 64 * 1536;
        f32x4 acc[2][2];
#pragma unroll
        for (int mf = 0; mf < 2; ++mf)
#pragma unroll
            for (int ni = 0; ni < 2; ++ni) acc[mf][ni] = (f32x4){0.f, 0.f, 0.f, 0.f};
#pragma unroll
        for (int ni = 0; ni < 2; ++ni) {
            acc[0][ni] = __builtin_amdgcn_mfma_f32_16x16x32_bf16(k00, qf[ni][0], acc[0][ni], 0, 0, 0);
            acc[0][ni] = __builtin_amdgcn_mfma_f32_16x16x32_bf16(k01, qf[ni][1], acc[0][ni], 0, 0, 0);
            acc[1][ni] = __builtin_amdgcn_mfma_f32_16x16x32_bf16(k10, qf[ni][0], acc[1][ni], 0, 0, 0);
            acc[1][ni] = __builtin_amdgcn_mfma_f32_16x16x32_bf16(k11, qf[ni][1], acc[1][ni], 0, 0, 0);
        }
        // normalized p -> Ps[js][h][i][j], packed b64 writes (j = mf*16+qq*4 .. +3)
#pragma unroll
        for (int mf = 0; mf < 2; ++mf)
#pragma unroll
            for (int ni = 0; ni < 2; ++ni) {
                float p0 = fast_exp2(acc[mf][ni][0] - llog[ni]);
                float p1 = fast_exp2(acc[mf][ni][1] - llog[ni]);
                float p2 = fast_exp2(acc[mf][ni][2] - llog[ni]);
                float p3 = fast_exp2(acc[mf][ni][3] - llog[ni]);
                uint2 pk2;
                pk2.x = cvt_pk_bf16(p0, p1);
                pk2.y = cvt_pk_bf16(p2, p3);
                *(uint2*)&Ps[psbase + (ni * 16 + lr) * 36 + mf * 16 + qq * 4] = pk2;
            }
        __syncthreads();  // A: Ps complete
        // remix + LN: lane owns points (i = pp*16+lr, j = jj) of its group's tile
#pragma unroll
        for (int pp = 0; pp < 2; ++pp) {
            const int i = pp * 16 + lr;
            float pv8[8];
#pragma unroll
            for (int hh = 0; hh < 8; ++hh)
                pv8[hh] = bf2f(Ps[(js * 8 + hh) * 32 * 36 + i * 36 + jj]);
            float mix[8];
#pragma unroll
            for (int g = 0; g < 8; ++g) mix[g] = 0.f;
#pragma unroll
            for (int hh = 0; hh < 8; ++hh)
#pragma unroll
                for (int g = 0; g < 8; ++g) mix[g] = fmaf(pv8[hh], wm[hh * 8 + g], mix[g]);
            float mu = 0.f;
#pragma unroll
            for (int g = 0; g < 8; ++g) mu += mix[g];
            mu *= 0.125f;
            float var = 0.f;
#pragma unroll
            for (int g = 0; g < 8; ++g) { float d = mix[g] - mu; var += d * d; }
            var *= 0.125f;
            float rs = rsqrtf(var + 1e-5f);
#pragma unroll
            for (int g = 0; g < 8; ++g)
                Rs[(js * 8 + g) * 32 * 36 + i * 36 + jj] =
                    f2bf((mix[g] - mu) * rs * gam[g] + bet[g]);
        }
        __syncthreads();  // B: Rs complete
        // PV: wave h consumes Rs[js][h] as A-frag, V as B-frag
#pragma unroll
        for (int pp = 0; pp < 2; ++pp) {
            bf16x4 alo = *(const bf16x4*)&Rs[psbase + (pp * 16 + lr) * 36 + qq * 8];
            bf16x4 ahi = *(const bf16x4*)&Rs[psbase + (pp * 16 + lr) * 36 + qq * 8 + 4];
            bf16x8 a = __builtin_shufflevector(alo, ahi, 0, 1, 2, 3, 4, 5, 6, 7);
#pragma unroll
            for (int nd = 0; nd < 4; ++nd) {
                bf16x8 bv = *(const bf16x8*)(vp[nd]);
                o[pp][nd] = __builtin_amdgcn_mfma_f32_16x16x32_bf16(a, bv, o[pp][nd], 0, 0, 0);
            }
        }
#pragma unroll
        for (int nd = 0; nd < 4; ++nd) vp[nd] += 64;
    }

    // ---- cross-group O merge + epilogue ----
    __syncthreads();
    if (js == 1) {
#pragma unroll
        for (int pp = 0; pp < 2; ++pp)
#pragma unroll
            for (int nd = 0; nd < 4; ++nd)
#pragma unroll
                for (int rr = 0; rr < 4; ++rr)
                    osum[(h * 32 + pp * 16 + qq * 4 + rr) * 64 + nd * 16 + lr] = o[pp][nd][rr];
    }
    __syncthreads();
    if (js == 0) {
#pragma unroll
        for (int pp = 0; pp < 2; ++pp)
#pragma unroll
            for (int nd = 0; nd < 4; ++nd)
#pragma unroll
                for (int rr = 0; rr < 4; ++rr) {
                    float v = o[pp][nd][rr] +
                              osum[(h * 32 + pp * 16 + qq * 4 + rr) * 64 + nd * 16 + lr];
                    pvout[(size_t)(b * 1024 + i0 + pp * 16 + qq * 4 + rr) * 512 +
                          h * 64 + nd * 16 + lr] = f2bf(v);
                }
    }
}

extern "C" void kernel_launch(void* const* d_in, const int* in_sizes, int n_in,
                              void* d_out, int out_size, void* d_ws, size_t ws_size,
                              hipStream_t stream) {
    const float* x        = (const float*)d_in[0];
    const float* w_qkv    = (const float*)d_in[1];
    const float* reattn_w = (const float*)d_in[2];
    const float* ln_g     = (const float*)d_in[3];
    const float* ln_b     = (const float*)d_in[4];
    const float* w_out    = (const float*)d_in[5];
    const float* b_out    = (const float*)d_in[6];
    float* out = (float*)d_out;

    char* ws = (char*)d_ws;
    unsigned short* x_bf  = (unsigned short*)(ws + 0);          //  8 MB  [8192][512]
    unsigned short* wqkvT = (unsigned short*)(ws + 8388608);    //  1.5MB [1536][512]
    unsigned short* woutT = (unsigned short*)(ws + 9961472);    //  0.5MB [512][512]
    unsigned short* qkv   = (unsigned short*)(ws + 10485760);   // 24 MB  [8192][1536]
    unsigned short* v_t   = (unsigned short*)(ws + 35651584);   //  8 MB  [64][64][1024]
    unsigned short* pv    = (unsigned short*)(ws + 44040192);   //  8 MB  [8192][512]

    k_f32_to_bf16<<<4096, 256, 0, stream>>>(x, x_bf, 1048576);
    k_transpose_bf16<<<3072, 256, 0, stream>>>(w_qkv, wqkvT, 512, 1536);
    k_transpose_bf16<<<1024, 256, 0, stream>>>(w_out, woutT, 512, 512);

    // qkv = x @ w_qkv   (M=8192, N=1536, K=512)
    gemm_bt<128, 128, 64, true, false><<<dim3(64, 12, 1), 256, 0, stream>>>(
        x_bf, 512, 0, wqkvT, 512, 0, qkv, 1536, 0, nullptr, 1.0f, 512);

    transpose_v<<<dim3(16, 64), 256, 0, stream>>>(qkv, v_t);

    // fused attention
    attn_fused<<<256, 1024, 0, stream>>>(qkv, v_t, pv, reattn_w, ln_g, ln_b);

    // out = pv @ w_out + b_out   (M=8192, N=512, K=512), fp32 out
    gemm_bt<128, 128, 64, false, true><<<dim3(64, 4, 1), 256, 0, stream>>>(
        pv, 512, 0, woutT, 512, 0, out, 512, 0, b_out, 1.0f, 512);
}